// Round 3
// baseline (285.888 us; speedup 1.0000x reference)
//
#include <hip/hip_runtime.h>
#include <math.h>

#define NBINS 256
#define NCOPY 16   // LDS sub-histogram copies; copy index = lane & 15

// Fused histogram for both inputs. torch.histc semantics over [-1,1], 256 bins.
// Binning in f32 exactly as the reference: floor((x+1) * 128), clip to 255,
// ignore out-of-range. ((x+1) is exact-rounded add; *128 = *2^7 is exact, so
// this matches (x - lo)/width bit-for-bit.)

__device__ __forceinline__ void proc4(float4 v, unsigned int* __restrict__ lh, int c) {
    float vv[4] = {v.x, v.y, v.z, v.w};
#pragma unroll
    for (int j = 0; j < 4; j++) {
        float f = vv[j];
        if (f >= -1.0f && f <= 1.0f) {
            // f+1 >= 0 exactly, so trunc == floor; value 256 only at f==1.0
            int bin = (int)((f + 1.0f) * 128.0f);
            bin = bin > (NBINS - 1) ? (NBINS - 1) : bin;
            atomicAdd(&lh[(bin << 4) + c], 1u);
        }
    }
}

// Access pattern: each block owns a CONTIGUOUS chunk (n4/half_blocks float4
// = 128 KB) and sweeps it in 4 KB steps. The previous grid-stride walked a
// 4 MB stride per iteration -> every load on a fresh 2 MB page -> ~65k TLB
// walks serialized on the page walkers (time was invariant to L3 vs HBM
// residency, all pipes idle => translation-bound, not data-bound).
// Contiguous chunks cut the per-block page footprint from 32 pages to ~1.
__global__ __launch_bounds__(256) void hist2_kernel(const float* __restrict__ a,
                                                    const float* __restrict__ b,
                                                    unsigned int* __restrict__ ghist,
                                                    int n4a, int n4b, int half_blocks) {
    __shared__ unsigned int lh[NBINS * NCOPY];  // 16 KB
    const int tid = threadIdx.x;
    for (int i = tid; i < NBINS * NCOPY; i += 256) lh[i] = 0u;
    __syncthreads();

    const int which = (blockIdx.x >= half_blocks) ? 1 : 0;
    const float4* __restrict__ x4 = (const float4*)(which ? b : a);
    const int n4 = which ? n4b : n4a;
    const int bid = which ? (blockIdx.x - half_blocks) : blockIdx.x;
    const int c = tid & (NCOPY - 1);

    const int chunk = (n4 + half_blocks - 1) / half_blocks;  // float4 per block
    const int beg = bid * chunk;
    const int end = (beg + chunk < n4) ? (beg + chunk) : n4;

    // 4x unroll, +4KB strides within the chunk; sched_barrier pins all 4
    // loads before any LDS-atomic processing so the wave keeps 4 VMEM ops
    // in flight (round-2 showed the compiler otherwise serializes them,
    // VGPR_Count=16).
    int i = beg + tid;
    for (; i + 3 * 256 < end; i += 4 * 256) {
        float4 v0 = x4[i];
        float4 v1 = x4[i + 256];
        float4 v2 = x4[i + 512];
        float4 v3 = x4[i + 768];
        __builtin_amdgcn_sched_barrier(0);
        proc4(v0, lh, c);
        proc4(v1, lh, c);
        proc4(v2, lh, c);
        proc4(v3, lh, c);
    }
    for (; i < end; i += 256) {
        proc4(x4[i], lh, c);
    }
    __syncthreads();

    // Fold 16 copies; one bin per thread (blockDim == NBINS)
    unsigned int s = 0;
#pragma unroll
    for (int k = 0; k < NCOPY; k++) s += lh[(tid << 4) + k];
    atomicAdd(&ghist[which * NBINS + tid], s);
}

// Entropy of both histograms + |diff|, all in double. One block of 256 threads.
__global__ __launch_bounds__(256) void entropy_kernel(const unsigned int* __restrict__ gh,
                                                      float* __restrict__ out) {
    __shared__ double sd[NBINS];
    const int tid = threadIdx.x;
    double e[2];

    for (int h = 0; h < 2; h++) {
        const double hv = (double)gh[h * NBINS + tid];

        sd[tid] = hv;
        __syncthreads();
        for (int o = 128; o > 0; o >>= 1) {
            if (tid < o) sd[tid] += sd[tid + o];
            __syncthreads();
        }
        const double total = sd[0];
        __syncthreads();

        const double p = hv / total + 1e-8;
        sd[tid] = -p * log(p);
        __syncthreads();
        for (int o = 128; o > 0; o >>= 1) {
            if (tid < o) sd[tid] += sd[tid + o];
            __syncthreads();
        }
        e[h] = sd[0];
        __syncthreads();
    }

    if (tid == 0) out[0] = (float)fabs(e[0] - e[1]);
}

extern "C" void kernel_launch(void* const* d_in, const int* in_sizes, int n_in,
                              void* d_out, int out_size, void* d_ws, size_t ws_size,
                              hipStream_t stream) {
    const float* pred = (const float*)d_in[0];
    const float* gt   = (const float*)d_in[1];
    const int n0 = in_sizes[0];
    const int n1 = in_sizes[1];

    unsigned int* hist = (unsigned int*)d_ws;  // [2][NBINS]
    hipMemsetAsync(d_ws, 0, 2 * NBINS * sizeof(unsigned int), stream);

    // 1024 blocks per input = 8 blocks/CU total; 16 KB LDS each -> full occupancy
    const int half_blocks = 1024;
    hist2_kernel<<<2 * half_blocks, 256, 0, stream>>>(pred, gt, hist,
                                                      n0 / 4, n1 / 4, half_blocks);
    entropy_kernel<<<1, 256, 0, stream>>>(hist, (float*)d_out);
}

// Round 4
// 282.510 us; speedup vs baseline: 1.0120x; 1.0120x over previous
//
#include <hip/hip_runtime.h>
#include <math.h>

#define NBINS 256
#define NCOPY 32   // 32 LDS sub-histogram copies; copy index = tid & 31
                   // addr = (bin<<5)+c  =>  bank = c exactly (bin<<5 == 0 mod 32):
                   // lanes 0-31 hit 32 DISTINCT banks, lanes 32-63 repeat them ->
                   // every wave64 ds_add is the 2-pass floor, data-independent.
                   // (Old NCOPY=16 layout used banks c+16*(bin&1): 4 lanes per c
                   // split across only 2 banks by bin PARITY -> ~60 cy/wave-atomic;
                   // 4096 wave-atomics/CU * 60cy == the entire 254k-cycle kernel.)

// Fused histogram for both inputs. torch.histc semantics over [-1,1], 256 bins.
// Binning in f32 exactly as the reference: floor((x+1) * 128), clip to 255,
// ignore out-of-range. ((x+1) rounds, *128 = *2^7 exact => bit-identical to
// (x - lo)/width with floor.)

__device__ __forceinline__ void proc4(float4 v, unsigned int* __restrict__ lh, int c) {
    float vv[4] = {v.x, v.y, v.z, v.w};
#pragma unroll
    for (int j = 0; j < 4; j++) {
        float f = vv[j];
        if (f >= -1.0f && f <= 1.0f) {
            // f+1 >= 0 exactly, so trunc == floor; value 256 only at f==1.0
            int bin = (int)((f + 1.0f) * 128.0f);
            bin = bin > (NBINS - 1) ? (NBINS - 1) : bin;
            atomicAdd(&lh[(bin << 5) + c], 1u);
        }
    }
}

__global__ __launch_bounds__(256) void hist2_kernel(const float* __restrict__ a,
                                                    const float* __restrict__ b,
                                                    unsigned int* __restrict__ ghist,
                                                    int n4a, int n4b, int half_blocks) {
    __shared__ unsigned int lh[NBINS * NCOPY];  // 32 KB -> 4 blocks/CU
    const int tid = threadIdx.x;
    for (int i = tid; i < NBINS * NCOPY; i += 256) lh[i] = 0u;
    __syncthreads();

    const int which = (blockIdx.x >= half_blocks) ? 1 : 0;
    const float4* __restrict__ x4 = (const float4*)(which ? b : a);
    const int n4 = which ? n4b : n4a;
    const int bid = which ? (blockIdx.x - half_blocks) : blockIdx.x;
    const int c = tid & (NCOPY - 1);

    // Contiguous 256 KB chunk per block, swept in 4 KB steps (kept from r3;
    // neutral then, but keeps the page footprint minimal once DS unblocks).
    const int chunk = (n4 + half_blocks - 1) / half_blocks;
    const int beg = bid * chunk;
    const int end = (beg + chunk < n4) ? (beg + chunk) : n4;

    int i = beg + tid;
    for (; i + 3 * 256 < end; i += 4 * 256) {
        float4 v0 = x4[i];
        float4 v1 = x4[i + 256];
        float4 v2 = x4[i + 512];
        float4 v3 = x4[i + 768];
        __builtin_amdgcn_sched_barrier(0);
        proc4(v0, lh, c);
        proc4(v1, lh, c);
        proc4(v2, lh, c);
        proc4(v3, lh, c);
    }
    for (; i < end; i += 256) {
        proc4(x4[i], lh, c);
    }
    __syncthreads();

    // Fold 32 copies; one bin per thread (blockDim == NBINS).
    // Diagonal rotation: lane t reads copy (k+t)&31 -> bank (k+t)&31, all 64
    // lanes on distinct-or-2-way banks instead of a 64-way pileup on bank k.
    unsigned int s = 0;
#pragma unroll
    for (int k = 0; k < NCOPY; k++) s += lh[(tid << 5) + ((k + tid) & (NCOPY - 1))];
    atomicAdd(&ghist[which * NBINS + tid], s);
}

// Entropy of both histograms + |diff|, all in double. One block of 256 threads.
__global__ __launch_bounds__(256) void entropy_kernel(const unsigned int* __restrict__ gh,
                                                      float* __restrict__ out) {
    __shared__ double sd[NBINS];
    const int tid = threadIdx.x;
    double e[2];

    for (int h = 0; h < 2; h++) {
        const double hv = (double)gh[h * NBINS + tid];

        sd[tid] = hv;
        __syncthreads();
        for (int o = 128; o > 0; o >>= 1) {
            if (tid < o) sd[tid] += sd[tid + o];
            __syncthreads();
        }
        const double total = sd[0];
        __syncthreads();

        const double p = hv / total + 1e-8;
        sd[tid] = -p * log(p);
        __syncthreads();
        for (int o = 128; o > 0; o >>= 1) {
            if (tid < o) sd[tid] += sd[tid + o];
            __syncthreads();
        }
        e[h] = sd[0];
        __syncthreads();
    }

    if (tid == 0) out[0] = (float)fabs(e[0] - e[1]);
}

extern "C" void kernel_launch(void* const* d_in, const int* in_sizes, int n_in,
                              void* d_out, int out_size, void* d_ws, size_t ws_size,
                              hipStream_t stream) {
    const float* pred = (const float*)d_in[0];
    const float* gt   = (const float*)d_in[1];
    const int n0 = in_sizes[0];
    const int n1 = in_sizes[1];

    unsigned int* hist = (unsigned int*)d_ws;  // [2][NBINS]
    hipMemsetAsync(d_ws, 0, 2 * NBINS * sizeof(unsigned int), stream);

    // 512 blocks per input; 1024 total = 4 blocks/CU at 32 KB LDS each.
    const int half_blocks = 512;
    hist2_kernel<<<2 * half_blocks, 256, 0, stream>>>(pred, gt, hist,
                                                      n0 / 4, n1 / 4, half_blocks);
    entropy_kernel<<<1, 256, 0, stream>>>(hist, (float*)d_out);
}